// Round 1
// baseline (668.481 us; speedup 1.0000x reference)
//
#include <hip/hip_runtime.h>
#include <cstdint>
#include <cstddef>

// Problem constants
constexpr int B_  = 4;
constexpr int C_  = 512;
constexpr int CH_ = 256;
constexpr int N_  = 4096;
#define LOG2E 1.4426950408889634f

typedef float  f32x4 __attribute__((ext_vector_type(4)));
typedef short  s16x8 __attribute__((ext_vector_type(8)));
typedef short  s16x4 __attribute__((ext_vector_type(4)));
typedef __bf16 bf16x8 __attribute__((ext_vector_type(8)));

__device__ __forceinline__ unsigned fbits(float x) { union { float f; unsigned u; } v; v.f = x; return v.u; }
__device__ __forceinline__ float bfloat(unsigned u) { union { float f; unsigned u; } v; v.u = u; return v.f; }
// round-to-nearest-even fp32 -> bf16 bits
__device__ __forceinline__ short bf16_rne(float x) {
  unsigned u = fbits(x);
  unsigned r = (u + 0x7FFFu + ((u >> 16) & 1u)) >> 16;
  return (short)r;
}
// truncating hi split; returns hi as float, writes bf16 bits
__device__ __forceinline__ float bf16_trunc(float x, short* h) {
  unsigned u = fbits(x) & 0xFFFF0000u;
  *h = (short)(u >> 16);
  return bfloat(u);
}

// 16x16x32 bf16 MFMA; frags carried as short8 bit patterns.
__device__ __forceinline__ f32x4 MFMA(s16x8 a, s16x8 b, f32x4 c) {
  return __builtin_amdgcn_mfma_f32_16x16x32_bf16(
      __builtin_bit_cast(bf16x8, a), __builtin_bit_cast(bf16x8, b), c, 0, 0, 0);
}

// async global->LDS, 16B per lane; lds base must be wave-uniform (HW adds lane*16)
typedef const __attribute__((address_space(1))) unsigned int* gas_u32p;
typedef __attribute__((address_space(3))) unsigned int* las_u32p;
__device__ __forceinline__ void async16(const void* g, void* l) {
  __builtin_amdgcn_global_load_lds((gas_u32p)g, (las_u32p)l, 16, 0, 0);
}

// ---------------------------------------------------------------------------
// Kernel 1: weight prep. Wq scaled by LOG2E (folds softmax exp->exp2),
// Wq/Wk split into bf16 hi(trunc)+lo(rne); Wv -> bf16 rne.
// ---------------------------------------------------------------------------
__global__ void prep_w_kernel(const float* __restrict__ Wq, const float* __restrict__ Wk,
                              const float* __restrict__ Wv,
                              short* __restrict__ wqh, short* __restrict__ wql,
                              short* __restrict__ wkh, short* __restrict__ wkl,
                              short* __restrict__ wvh) {
  int i = blockIdx.x * 256 + threadIdx.x;
  if (i < CH_ * C_) {
    float xq = Wq[i] * LOG2E;
    short h;
    float hf = bf16_trunc(xq, &h);
    wqh[i] = h; wql[i] = bf16_rne(xq - hf);
    float xk = Wk[i];
    hf = bf16_trunc(xk, &h);
    wkh[i] = h; wkl[i] = bf16_rne(xk - hf);
  }
  if (i < C_ * C_) wvh[i] = bf16_rne(Wv[i]);
}

// ---------------------------------------------------------------------------
// Kernel 2: projection GEMM  out[o][n] = sum_c W[o][c] X[b][c][n] + bias[o]
// A (weights) pre-split bf16 hi/lo in LDS (3-pass MFMA: Wh*Xh + Wh*Xl + Wl*Xh
// gives ~fp32-accurate result). B (X) read straight from global fp32,
// converted to hi/lo frags in-register.
// mode 0: store transposed [B][N][M] (hi, optional lo)   (q, k)
// mode 1: store natural    [B][M][N] (hi only)           (v)
// wg: 256 thr = 4 waves; wg-tile 128o x 64n; wave-tile 64o x 32n.
// ---------------------------------------------------------------------------
__global__ __launch_bounds__(256, 3) void proj_kernel(
    const short* __restrict__ Ah, const short* __restrict__ Al,
    const float* __restrict__ X, const float* __restrict__ bias, float bias_scale,
    short* __restrict__ outh, short* __restrict__ outl, int M, int mode) {
  // LDS W tiles, split-block layout [gh:2][row:128][c:16] to keep ds_read_b128
  // conflicts at 4-way instead of 16-way.
  __shared__ __align__(16) short lWh[2 * 128 * 16];
  __shared__ __align__(16) short lWl[2 * 128 * 16];

  const int tid = threadIdx.x;
  const int lane = tid & 63, wave = tid >> 6;
  const int g = lane >> 4, lm = lane & 15;
  const int b = blockIdx.z;
  const int o0 = blockIdx.y * 128;
  const int n0 = blockIdx.x * 64;
  const int wo = (wave & 1) * 64;
  const int wn = (wave >> 1) * 32;
  const bool hasAl = (Al != nullptr);
  const bool hasOl = (outl != nullptr);

  f32x4 acc[4][2];
#pragma unroll
  for (int i = 0; i < 4; ++i)
#pragma unroll
    for (int j = 0; j < 2; ++j) acc[i][j] = f32x4{0.f, 0.f, 0.f, 0.f};

  const float* Xb = X + (size_t)b * C_ * N_;

  for (int c0 = 0; c0 < C_; c0 += 32) {
    __syncthreads();
    // stage W tiles [128][32] as [gh][row][16]; 512 chunks of 16B per tile
#pragma unroll
    for (int r = 0; r < 2; ++r) {
      int ci = r * 256 + tid;
      int gh = ci >> 8, row = (ci >> 1) & 127, ch = ci & 1;
      const short* gs = Ah + (size_t)(o0 + row) * C_ + c0 + gh * 16 + ch * 8;
      async16(gs, (char*)lWh + r * 4096 + wave * 1024);
      if (hasAl) {
        const short* gs2 = Al + (size_t)(o0 + row) * C_ + c0 + gh * 16 + ch * 8;
        async16(gs2, (char*)lWl + r * 4096 + wave * 1024);
      }
    }
    __syncthreads();

    // B frags from global fp32 (coalesced 64B per 16-lane group per c-row)
    s16x8 xh[2], xl[2];
#pragma unroll
    for (int nt = 0; nt < 2; ++nt) {
      int n_g = n0 + wn + nt * 16 + lm;
      const float* xp = Xb + (size_t)(c0 + g * 8) * N_ + n_g;
#pragma unroll
      for (int j = 0; j < 8; ++j) {
        float xv = xp[(size_t)j * N_];
        unsigned u = fbits(xv);
        unsigned hb = u & 0xFFFF0000u;
        xh[nt][j] = (short)(hb >> 16);
        if (hasAl) {
          float rem = xv - bfloat(hb);
          xl[nt][j] = bf16_rne(rem);
        }
      }
    }

#pragma unroll
    for (int ot = 0; ot < 4; ++ot) {
      int row = wo + ot * 16 + lm;
      s16x8 wh = *(const s16x8*)&lWh[(g >> 1) * 2048 + row * 16 + (g & 1) * 8];
#pragma unroll
      for (int nt = 0; nt < 2; ++nt) acc[ot][nt] = MFMA(wh, xh[nt], acc[ot][nt]);
      if (hasAl) {
        s16x8 wl = *(const s16x8*)&lWl[(g >> 1) * 2048 + row * 16 + (g & 1) * 8];
#pragma unroll
        for (int nt = 0; nt < 2; ++nt) {
          acc[ot][nt] = MFMA(wh, xl[nt], acc[ot][nt]);
          acc[ot][nt] = MFMA(wl, xh[nt], acc[ot][nt]);
        }
      }
    }
  }

  // epilogue: bias + store
#pragma unroll
  for (int ot = 0; ot < 4; ++ot) {
    int o4 = o0 + wo + ot * 16 + g * 4;
    f32x4 bb = *(const f32x4*)&bias[o4];
#pragma unroll
    for (int nt = 0; nt < 2; ++nt) {
      int n_g = n0 + wn + nt * 16 + lm;
      float val[4];
#pragma unroll
      for (int r = 0; r < 4; ++r) val[r] = acc[ot][nt][r] + bb[r] * bias_scale;
      if (mode == 0) {
        size_t base = ((size_t)b * N_ + n_g) * (size_t)M + o4;
        s16x4 hs, ls;
#pragma unroll
        for (int r = 0; r < 4; ++r) {
          if (hasOl) {
            short h;
            float hf = bf16_trunc(val[r], &h);
            hs[r] = h;
            ls[r] = bf16_rne(val[r] - hf);
          } else {
            hs[r] = bf16_rne(val[r]);
          }
        }
        *(s16x4*)(outh + base) = hs;
        if (hasOl) *(s16x4*)(outl + base) = ls;
      } else {
#pragma unroll
        for (int r = 0; r < 4; ++r)
          outh[((size_t)b * M + o4 + r) * (size_t)N_ + n_g] = bf16_rne(val[r]);
      }
    }
  }
}

// ---------------------------------------------------------------------------
// Kernel 3: flash attention.
// grid 256 (XCD-swizzled), 512 threads (8 waves), Q-tile 64 rows, K-tile 32.
// q frags (hi+lo) cached in registers. S = (qh+ql)*kh (2-pass).
// Online softmax in exp2 domain (q pre-scaled by log2e).
// PV computes O^T = V*P^T so stores are [c][n]-coalesced.
// ---------------------------------------------------------------------------
__global__ __launch_bounds__(512, 2) void attn_kernel(
    const short* __restrict__ qTh, const short* __restrict__ qTl,
    const short* __restrict__ kTh, const short* __restrict__ vN,
    const float* __restrict__ Vin, const float* __restrict__ gptr,
    float* __restrict__ out) {
  // kh: [kc2:16][m:32][c:16]  (16 KB)
  __shared__ __align__(16) short kh_t[16 * 32 * 16];
  // v: [half:2][c:512][m:16]  (32 KB); also q staging buffer [n:64][c:256]
  __shared__ __align__(16) short v_t[2 * 512 * 16];
  __shared__ __align__(16) float S_t[64 * 36];  // padded stride 36
  __shared__ __align__(16) short P_t[64 * 40];  // padded stride 40
  __shared__ float m_st[64], l_st[64], al_st[64];
  __shared__ int rflag;

  const int tid = threadIdx.x;
  const int lane = tid & 63, wave = tid >> 6;
  const int g = lane >> 4, lm = lane & 15;

  // XCD-aware swizzle: batch constant per XCD-pair for K/V L2 locality
  int bx = blockIdx.x;
  int xcd = bx & 7, slot = bx >> 3;
  int b = xcd >> 1;
  int tile = (xcd & 1) * 32 + slot;
  int n0 = tile * 64;

  const int rt = wave & 3;    // S row-tile (query rows)
  const int ctS = wave >> 2;  // S col-tile (keys 0-15 / 16-31)
  const int c0w = wave * 64;  // PV: this wave's channel range

  f32x4 O[4][4];
#pragma unroll
  for (int i = 0; i < 4; ++i)
#pragma unroll
    for (int j = 0; j < 4; ++j) O[i][j] = f32x4{0.f, 0.f, 0.f, 0.f};

  if (tid < 64) { m_st[tid] = -1e30f; l_st[tid] = 0.f; }

  // ---- prologue: load q frags (hi then lo) through v_t buffer ----
  const size_t qoff = ((size_t)b * N_ + n0) * CH_;
  s16x8 qh[8], ql[8];
#pragma unroll
  for (int r = 0; r < 4; ++r)
    async16((const char*)(qTh + qoff) + r * 8192 + tid * 16, (char*)v_t + r * 8192 + wave * 1024);
  __syncthreads();
#pragma unroll
  for (int ks = 0; ks < 8; ++ks)
    qh[ks] = *(const s16x8*)&v_t[(rt * 16 + lm) * 256 + ks * 32 + g * 8];
  __syncthreads();
#pragma unroll
  for (int r = 0; r < 4; ++r)
    async16((const char*)(qTl + qoff) + r * 8192 + tid * 16, (char*)v_t + r * 8192 + wave * 1024);
  __syncthreads();
#pragma unroll
  for (int ks = 0; ks < 8; ++ks)
    ql[ks] = *(const s16x8*)&v_t[(rt * 16 + lm) * 256 + ks * 32 + g * 8];

  const short* kTb = kTh + (size_t)b * N_ * CH_;
  const short* vNb = vN + (size_t)b * C_ * N_;

#pragma unroll 1
  for (int it = 0; it < 128; ++it) {
    const int m0 = it * 32;
    __syncthreads();  // protects v_t/kh_t/P_t reuse across iterations
    if (tid == 0) rflag = 0;
    // stage kh tile: 1024 16B chunks, layout [kc2][m][ch]
#pragma unroll
    for (int r = 0; r < 2; ++r) {
      int idx = r * 512 + tid;
      int kc2 = idx >> 6, mm = (idx >> 1) & 31, ch = idx & 1;
      const short* gs = kTb + (size_t)(m0 + mm) * CH_ + kc2 * 16 + ch * 8;
      async16(gs, (char*)kh_t + r * 8192 + wave * 1024);
    }
    // stage v tile: 2048 16B chunks, layout [half][c][ch]
#pragma unroll
    for (int r = 0; r < 4; ++r) {
      int idx = r * 512 + tid;
      int half = idx >> 10, cc = (idx >> 1) & 511, ch = idx & 1;
      const short* gs = vNb + (size_t)cc * N_ + m0 + half * 16 + ch * 8;
      async16(gs, (char*)v_t + r * 8192 + wave * 1024);
    }
    __syncthreads();

    // ---- S phase: each wave one 16x16 S tile, K=256, 2 passes ----
    f32x4 s = f32x4{0.f, 0.f, 0.f, 0.f};
#pragma unroll
    for (int ks = 0; ks < 8; ++ks) {
      const s16x8 bk = *(const s16x8*)&kh_t[(ks * 2 + (g >> 1)) * 512 + (ctS * 16 + lm) * 16 + (g & 1) * 8];
      s = MFMA(qh[ks], bk, s);
      s = MFMA(ql[ks], bk, s);
    }
    {
      int row = rt * 16 + g * 4;
      int col = ctS * 16 + lm;
#pragma unroll
      for (int r = 0; r < 4; ++r) S_t[(row + r) * 36 + col] = s[r];
    }
    __syncthreads();

    // ---- online softmax: 8 threads per row, 4 cols each ----
    {
      int row = tid >> 3, q8 = tid & 7;
      f32x4 sv = *(const f32x4*)&S_t[row * 36 + q8 * 4];
      float mx = fmaxf(fmaxf(sv[0], sv[1]), fmaxf(sv[2], sv[3]));
      mx = fmaxf(mx, __shfl_xor(mx, 1));
      mx = fmaxf(mx, __shfl_xor(mx, 2));
      mx = fmaxf(mx, __shfl_xor(mx, 4));
      float mo = m_st[row];
      float mn = fmaxf(mo, mx);
      float a = exp2f(mo - mn);
      float p0 = exp2f(sv[0] - mn), p1 = exp2f(sv[1] - mn);
      float p2 = exp2f(sv[2] - mn), p3 = exp2f(sv[3] - mn);
      float lsum = (p0 + p1) + (p2 + p3);
      lsum += __shfl_xor(lsum, 1);
      lsum += __shfl_xor(lsum, 2);
      lsum += __shfl_xor(lsum, 4);
      if (q8 == 0) {
        al_st[row] = a;
        if (mn > mo) rflag = 1;
        m_st[row] = mn;
        l_st[row] = l_st[row] * a + lsum;
      }
      s16x4 pp;
      pp[0] = bf16_rne(p0); pp[1] = bf16_rne(p1);
      pp[2] = bf16_rne(p2); pp[3] = bf16_rne(p3);
      *(s16x4*)&P_t[row * 40 + q8 * 4] = pp;
    }
    __syncthreads();

    // ---- rescale O (usually skipped: running max rarely changes) ----
    if (rflag) {
#pragma unroll
      for (int nt = 0; nt < 4; ++nt) {
        float a = al_st[nt * 16 + lm];
#pragma unroll
        for (int ct = 0; ct < 4; ++ct) {
          O[ct][nt][0] *= a; O[ct][nt][1] *= a;
          O[ct][nt][2] *= a; O[ct][nt][3] *= a;
        }
      }
    }

    // ---- PV phase: O^T[c][n] += sum_m v[c][m] * P[n][m] ----
    s16x8 vf[4];
#pragma unroll
    for (int ct = 0; ct < 4; ++ct)
      vf[ct] = *(const s16x8*)&v_t[(g >> 1) * 8192 + (c0w + ct * 16 + lm) * 16 + (g & 1) * 8];
#pragma unroll
    for (int nt = 0; nt < 4; ++nt) {
      const s16x8 pf = *(const s16x8*)&P_t[(nt * 16 + lm) * 40 + g * 8];
#pragma unroll
      for (int ct = 0; ct < 4; ++ct) O[ct][nt] = MFMA(vf[ct], pf, O[ct][nt]);
    }
  }

  // ---- epilogue: out = gamma * O/l + V, coalesced [c][n] stores ----
  const float gamma = gptr[0];
  const float* Vb = Vin + (size_t)b * C_ * N_;
  float* outb = out + (size_t)b * C_ * N_;
#pragma unroll
  for (int nt = 0; nt < 4; ++nt) {
    int n_g = n0 + nt * 16 + lm;
    float rl = gamma / l_st[nt * 16 + lm];
#pragma unroll
    for (int ct = 0; ct < 4; ++ct) {
      int cbase = c0w + ct * 16 + g * 4;
#pragma unroll
      for (int r = 0; r < 4; ++r) {
        size_t idx = (size_t)(cbase + r) * N_ + n_g;
        outb[idx] = O[ct][nt][r] * rl + Vb[idx];
      }
    }
  }
}

// ---------------------------------------------------------------------------
extern "C" void kernel_launch(void* const* d_in, const int* in_sizes, int n_in,
                              void* d_out, int out_size, void* d_ws, size_t ws_size,
                              hipStream_t stream) {
  const float* Q  = (const float*)d_in[0];
  const float* K  = (const float*)d_in[1];
  const float* V  = (const float*)d_in[2];
  const float* Wq = (const float*)d_in[3];
  const float* bq = (const float*)d_in[4];
  const float* Wk = (const float*)d_in[5];
  const float* bk = (const float*)d_in[6];
  const float* Wv = (const float*)d_in[7];
  const float* bv = (const float*)d_in[8];
  const float* gm = (const float*)d_in[9];
  float* out = (float*)d_out;

  // workspace carve (43.5 MB total)
  char* p = (char*)d_ws;
  short* wqh = (short*)p; p += (size_t)CH_ * C_ * 2;
  short* wql = (short*)p; p += (size_t)CH_ * C_ * 2;
  short* wkh = (short*)p; p += (size_t)CH_ * C_ * 2;
  short* wkl = (short*)p; p += (size_t)CH_ * C_ * 2;
  short* wvh = (short*)p; p += (size_t)C_ * C_ * 2;
  short* qTh = (short*)p; p += (size_t)B_ * N_ * CH_ * 2;
  short* qTl = (short*)p; p += (size_t)B_ * N_ * CH_ * 2;
  short* kTh = (short*)p; p += (size_t)B_ * N_ * CH_ * 2;
  short* v_n = (short*)p; p += (size_t)B_ * C_ * N_ * 2;

  prep_w_kernel<<<(C_ * C_) / 256, 256, 0, stream>>>(Wq, Wk, Wv, wqh, wql, wkh, wkl, wvh);

  // q: 3-pass, hi+lo out, bias scaled by log2e (W already scaled)
  proj_kernel<<<dim3(N_ / 64, CH_ / 128, B_), 256, 0, stream>>>(
      wqh, wql, Q, bq, LOG2E, qTh, qTl, CH_, 0);
  // k: 3-pass, hi-only out
  proj_kernel<<<dim3(N_ / 64, CH_ / 128, B_), 256, 0, stream>>>(
      wkh, wkl, K, bk, 1.0f, kTh, nullptr, CH_, 0);
  // v: 1-pass, natural layout
  proj_kernel<<<dim3(N_ / 64, C_ / 128, B_), 256, 0, stream>>>(
      wvh, nullptr, V, bv, 1.0f, v_n, nullptr, C_, 1);

  attn_kernel<<<B_ * (N_ / 64), 512, 0, stream>>>(qTh, qTl, kTh, v_n, V, gm, out);
}

// Round 2
// 488.661 us; speedup vs baseline: 1.3680x; 1.3680x over previous
//
#include <hip/hip_runtime.h>
#include <cstdint>
#include <cstddef>

// Problem constants
constexpr int B_  = 4;
constexpr int C_  = 512;
constexpr int CH_ = 256;
constexpr int N_  = 4096;
#define LOG2E 1.4426950408889634f

typedef float    f32x4 __attribute__((ext_vector_type(4)));
typedef _Float16 f16x8 __attribute__((ext_vector_type(8)));

__device__ __forceinline__ f32x4 MFMA16(f16x8 a, f16x8 b, f32x4 c) {
  return __builtin_amdgcn_mfma_f32_16x16x32_f16(a, b, c, 0, 0, 0);
}

// async global->LDS, 16B per lane; LDS dest is wave-uniform base + lane*16
typedef const __attribute__((address_space(1))) unsigned int* gas_u32p;
typedef __attribute__((address_space(3))) unsigned int* las_u32p;
__device__ __forceinline__ void async16(const void* g, void* l) {
  __builtin_amdgcn_global_load_lds((gas_u32p)g, (las_u32p)l, 16, 0, 0);
}

// DPP 16-lane max reduction (row_ror 8/4/2/1) — VALU only, no LDS traffic
template <int CTRL>
__device__ __forceinline__ float dppmax(float x) {
  float y = __builtin_bit_cast(
      float, __builtin_amdgcn_update_dpp(0, __builtin_bit_cast(int, x), CTRL,
                                         0xF, 0xF, true));
  return fmaxf(x, y);
}
__device__ __forceinline__ float rowmax16(float x) {
  x = dppmax<0x128>(x);
  x = dppmax<0x124>(x);
  x = dppmax<0x122>(x);
  x = dppmax<0x121>(x);
  return x;
}

// ---------------------------------------------------------------------------
// Kernel 1: weight prep -> fp16. Wq (and bq, at proj time) scaled by LOG2E so
// softmax runs in native exp2 domain.
// ---------------------------------------------------------------------------
__global__ void prep_w_kernel(const float* __restrict__ Wq,
                              const float* __restrict__ Wk,
                              const float* __restrict__ Wv,
                              _Float16* __restrict__ wq,
                              _Float16* __restrict__ wk,
                              _Float16* __restrict__ wv) {
  int i = blockIdx.x * 256 + threadIdx.x;
  if (i < CH_ * C_) {
    wq[i] = (_Float16)(Wq[i] * LOG2E);
    wk[i] = (_Float16)Wk[i];
  }
  if (i < C_ * C_) wv[i] = (_Float16)Wv[i];
}

// ---------------------------------------------------------------------------
// Kernel 2: transpose+convert  X fp32 [b][c][n] -> Xt fp16 [b][n][c].
// 64x64 tile through LDS (pad 65 f32); coalesced read and write.
// ---------------------------------------------------------------------------
__global__ __launch_bounds__(256) void transpose_kernel(
    const float* __restrict__ X, _Float16* __restrict__ Xt) {
  __shared__ float lX[64 * 65];
  const int t = threadIdx.x;
  const int n0 = blockIdx.x * 64, c0 = blockIdx.y * 64, b = blockIdx.z;
  const float* src = X + ((size_t)b * C_ + c0) * N_ + n0;
#pragma unroll
  for (int p = 0; p < 4; ++p) {
    int c = p * 16 + (t >> 4);
    int n4 = (t & 15) * 4;
    f32x4 v = *(const f32x4*)(src + (size_t)c * N_ + n4);
#pragma unroll
    for (int i = 0; i < 4; ++i) lX[c * 65 + n4 + i] = v[i];
  }
  __syncthreads();
  const int n = t >> 2, cq = (t & 3) * 16;
  _Float16* dst = Xt + ((size_t)b * N_ + n0 + n) * C_ + c0 + cq;
  f16x8 o0, o1;
#pragma unroll
  for (int i = 0; i < 8; ++i) o0[i] = (_Float16)lX[(cq + i) * 65 + n];
#pragma unroll
  for (int i = 0; i < 8; ++i) o1[i] = (_Float16)lX[(cq + 8 + i) * 65 + n];
  *(f16x8*)dst = o0;
  *(f16x8*)(dst + 8) = o1;
}

// ---------------------------------------------------------------------------
// Kernel 3: projection GEMM, fp16 single-pass.
//   out[o][n] = sum_c W[o][c] * X[c][n] + bias[o]
// W fp16 [o][c] and Xt fp16 [b][n][c] both staged via async16 (double-buffered,
// one barrier per K-step), fragments read as ds_read_b128.
// mode 0: A=Xt,B=W -> D[n][o], store [b][n][M] (q,k). mode 1: A=W,B=Xt ->
// D[o][n], store [b][M][n] (v).  512 thr / 8 waves; wg tile 256o x 64n.
// ---------------------------------------------------------------------------
__global__ __launch_bounds__(512, 2) void proj_kernel(
    const _Float16* __restrict__ W, const _Float16* __restrict__ Xt,
    const float* __restrict__ bias, float bias_scale,
    _Float16* __restrict__ out, int M, int mode) {
  __shared__ _Float16 lW[2][256 * 32];  // 16 KB per buf
  __shared__ _Float16 lX[2][64 * 32];   // 4 KB per buf

  const int tid = threadIdx.x;
  const int lane = tid & 63, wave = tid >> 6;
  const int g = lane >> 4, lm = lane & 15;
  const int b = blockIdx.z;
  const int n0 = blockIdx.x * 64;
  const int o0 = blockIdx.y * 256;
  const int wo = (wave >> 1) * 64, wn = (wave & 1) * 32;

  const _Float16* Wb = W + (size_t)o0 * C_;
  const _Float16* Xb = Xt + ((size_t)b * N_ + n0) * C_;

  f32x4 acc[8];
#pragma unroll
  for (int i = 0; i < 8; ++i) acc[i] = f32x4{0.f, 0.f, 0.f, 0.f};

  auto stage = [&](int s, int buf) {
    int c0 = s * 32;
#pragma unroll
    for (int r = 0; r < 2; ++r) {  // W: 1024 granules
      int ci = r * 512 + tid;
      int o = ci >> 2, cg = ci & 3;
      async16(Wb + (size_t)o * C_ + c0 + cg * 8,
              (char*)&lW[buf][0] + r * 8192 + wave * 1024);
    }
    if (wave < 4) {  // X: 256 granules
      int n = tid >> 2, cg = tid & 3;
      async16(Xb + (size_t)n * C_ + c0 + cg * 8,
              (char*)&lX[buf][0] + wave * 1024);
    }
  };
  stage(0, 0);

  for (int s = 0; s < 16; ++s) {
    __syncthreads();
    if (s < 15) stage(s + 1, (s + 1) & 1);
    const _Float16* pw = &lW[s & 1][0];
    const _Float16* px = &lX[s & 1][0];
    f16x8 wf[4], xf[2];
#pragma unroll
    for (int ot = 0; ot < 4; ++ot)
      wf[ot] = *(const f16x8*)(pw + ((wo + ot * 16 + lm) * 4 + g) * 8);
#pragma unroll
    for (int nt = 0; nt < 2; ++nt)
      xf[nt] = *(const f16x8*)(px + ((wn + nt * 16 + lm) * 4 + g) * 8);
    if (mode == 0) {
#pragma unroll
      for (int nt = 0; nt < 2; ++nt)
#pragma unroll
        for (int ot = 0; ot < 4; ++ot)
          acc[nt * 4 + ot] = MFMA16(xf[nt], wf[ot], acc[nt * 4 + ot]);
    } else {
#pragma unroll
      for (int ot = 0; ot < 4; ++ot)
#pragma unroll
        for (int nt = 0; nt < 2; ++nt)
          acc[ot * 2 + nt] = MFMA16(wf[ot], xf[nt], acc[ot * 2 + nt]);
    }
  }

  if (mode == 0) {
    // D[n][o]: row=n=(g*4+r), col=o=lm
#pragma unroll
    for (int nt = 0; nt < 2; ++nt) {
#pragma unroll
      for (int ot = 0; ot < 4; ++ot) {
        int o = wo + ot * 16 + lm;  // o0 == 0 for q/k
        float bv = bias[o] * bias_scale;
#pragma unroll
        for (int r = 0; r < 4; ++r) {
          int n = n0 + wn + nt * 16 + g * 4 + r;
          out[((size_t)b * N_ + n) * M + o] =
              (_Float16)(acc[nt * 4 + ot][r] + bv);
        }
      }
    }
  } else {
    // D[o][n]: row=o=(g*4+r), col=n=lm
#pragma unroll
    for (int ot = 0; ot < 4; ++ot) {
#pragma unroll
      for (int r = 0; r < 4; ++r) {
        int o = o0 + wo + ot * 16 + g * 4 + r;
        float bv = bias[o];
#pragma unroll
        for (int nt = 0; nt < 2; ++nt) {
          int n = n0 + wn + nt * 16 + lm;
          out[((size_t)b * M + o) * N_ + n] =
              (_Float16)(acc[ot * 2 + nt][r] + bv);
        }
      }
    }
  }
}

// ---------------------------------------------------------------------------
// Kernel 4: flash attention, fp16 single-pass.
// grid 256 (XCD-swizzled), 512 thr / 8 waves, Q-tile 64, K-tile 32, 128 iters.
// q frags in regs; kh single-buffer LDS (XOR-swizzled granules), prefetched
// AFTER the last mid-iter barrier so the vmcnt(0) drain lands a full PV-phase
// later; v frags straight from global (no LDS), also prefetched one iter ahead.
// Softmax: DPP row-max (no LDS round-trip); row-sum l via ones-row MFMA in PV.
// ---------------------------------------------------------------------------
__global__ __launch_bounds__(512, 2) void attn_kernel(
    const _Float16* __restrict__ qT, const _Float16* __restrict__ kT,
    const _Float16* __restrict__ vN, const float* __restrict__ Vin,
    const float* __restrict__ gptr, float* __restrict__ out) {
  __shared__ _Float16 stage[16384];  // 32 KB: q staging; loop uses [0:16KB) for kh
  __shared__ _Float16 P_t[64 * 40];  // P[n][m], stride 40 halves (80 B, 16-aligned)
  __shared__ float sm[128];          // [ctS][row] strip maxes
  __shared__ float al_st[64];        // per-row alpha
  __shared__ float l_fin[64];

  const int tid = threadIdx.x;
  const int lane = tid & 63, wave = tid >> 6;
  const int g = lane >> 4, lm = lane & 15;

  // XCD-aware swizzle: batch constant per XCD-pair for K/V L2 locality
  const int bx = blockIdx.x;
  const int xcd = bx & 7, slot = bx >> 3;
  const int b = xcd >> 1;
  const int n0 = ((xcd & 1) * 32 + slot) * 64;

  const int rt = wave & 3;    // S row-tile (query rows)
  const int ctS = wave >> 2;  // S col-tile (keys 0-15 / 16-31)
  const int c0w = wave * 64;  // PV channel range

  f32x4 O[4][4];  // [ct][nt]
#pragma unroll
  for (int i = 0; i < 4; ++i)
#pragma unroll
    for (int j = 0; j < 4; ++j) O[i][j] = f32x4{0.f, 0.f, 0.f, 0.f};
  f32x4 Ol[4];  // ones-row accumulator (l), meaningful on wave 7
#pragma unroll
  for (int j = 0; j < 4; ++j) Ol[j] = f32x4{0.f, 0.f, 0.f, 0.f};

  // ---- prologue: q staging (2048 granules, XOR-swizzled) ----
  const _Float16* qTb = qT + ((size_t)b * N_ + n0) * CH_;
#pragma unroll
  for (int r = 0; r < 4; ++r) {
    int ci = r * 512 + tid;
    int n = ci >> 5, cgl = ci & 31;
    int cg = cgl ^ (n & 7);
    async16(qTb + (size_t)n * CH_ + cg * 8,
            (char*)stage + r * 8192 + wave * 1024);
  }
  __syncthreads();
  f16x8 qf[8];
  {
    int n = rt * 16 + lm;
#pragma unroll
    for (int ks = 0; ks < 8; ++ks) {
      int cg = (ks * 4 + g) ^ (n & 7);
      qf[ks] = *(const f16x8*)&stage[(n * 32 + cg) * 8];
    }
  }
  __syncthreads();  // all q reads done before kh overwrites stage

  const _Float16* kTb = kT + (size_t)b * N_ * CH_;
  const _Float16* vNb = vN + (size_t)b * C_ * N_;

  auto stage_k = [&](int it) {
    int m0 = it * 32;
#pragma unroll
    for (int r = 0; r < 2; ++r) {  // 1024 granules, XOR-swizzled
      int ci = r * 512 + tid;
      int m = ci >> 5, cgl = ci & 31;
      int cg = cgl ^ (m & 7);
      async16(kTb + (size_t)(m0 + m) * CH_ + cg * 8,
              (char*)stage + r * 8192 + wave * 1024);
    }
  };
  stage_k(0);

  f16x8 vf[4], vfn[4];
  const _Float16* vbase[4];
#pragma unroll
  for (int ct = 0; ct < 4; ++ct)
    vbase[ct] = vNb + (size_t)(c0w + ct * 16 + lm) * N_ + g * 8;
#pragma unroll
  for (int ct = 0; ct < 4; ++ct) vf[ct] = *(const f16x8*)(vbase[ct]);

  f32x4 m_run = f32x4{-1e30f, -1e30f, -1e30f, -1e30f};
  int kfo[8];  // loop-invariant k-frag offsets
  {
    int m = ctS * 16 + lm;
#pragma unroll
    for (int ks = 0; ks < 8; ++ks)
      kfo[ks] = (m * 32 + ((ks * 4 + g) ^ (m & 7))) * 8;
  }
  f16x8 ones;
#pragma unroll
  for (int i = 0; i < 8; ++i) ones[i] = (_Float16)1.0f;

#pragma unroll 1
  for (int it = 0; it < 128; ++it) {
    __syncthreads();  // drains kh(it)+vf prefetch (issued one phase ago); P_t reuse

    // ---- S: one 16x16 tile per wave, K=256, single fp16 pass ----
    f32x4 s = f32x4{0.f, 0.f, 0.f, 0.f};
#pragma unroll
    for (int ks = 0; ks < 8; ++ks) {
      f16x8 kf = *(const f16x8*)&stage[kfo[ks]];
      s = MFMA16(qf[ks], kf, s);
    }

    // ---- strip row-max via DPP, exchange across the 2 col-waves ----
    f32x4 mx;
#pragma unroll
    for (int r = 0; r < 4; ++r) mx[r] = rowmax16(s[r]);
    if (lm == 0) *(f32x4*)&sm[ctS * 64 + rt * 16 + g * 4] = mx;
    __syncthreads();  // B
    f32x4 a0 = *(const f32x4*)&sm[rt * 16 + g * 4];
    f32x4 a1 = *(const f32x4*)&sm[64 + rt * 16 + g * 4];
    f32x4 mn, alpha;
#pragma unroll
    for (int r = 0; r < 4; ++r) {
      mn[r] = fmaxf(m_run[r], fmaxf(a0[r], a1[r]));
      alpha[r] = exp2f(m_run[r] - mn[r]);
      m_run[r] = mn[r];
    }
#pragma unroll
    for (int r = 0; r < 4; ++r) {
      float p = exp2f(s[r] - mn[r]);
      P_t[(rt * 16 + g * 4 + r) * 40 + ctS * 16 + lm] = (_Float16)p;
    }
    if (ctS == 0 && lm == 0) *(f32x4*)&al_st[rt * 16 + g * 4] = alpha;
    __syncthreads();  // C — last barrier before next iter's top barrier

    // ---- prefetch next tiles: issued here so the only vmcnt(0) drain they
    // meet (next top barrier) is a full PV phase later ----
    if (it < 127) {
      stage_k(it + 1);
      int mo = (it + 1) * 32;
#pragma unroll
      for (int ct = 0; ct < 4; ++ct)
        vfn[ct] = *(const f16x8*)(vbase[ct] + mo);
    }

    // ---- rescale O (and l-accumulator) by alpha[n] ----
#pragma unroll
    for (int nt = 0; nt < 4; ++nt) {
      float a = al_st[nt * 16 + lm];
#pragma unroll
      for (int ct = 0; ct < 4; ++ct) {
        O[ct][nt][0] *= a; O[ct][nt][1] *= a;
        O[ct][nt][2] *= a; O[ct][nt][3] *= a;
      }
      Ol[nt][0] *= a; Ol[nt][1] *= a; Ol[nt][2] *= a; Ol[nt][3] *= a;
    }

    // ---- PV: O^T[c][n] += v[c][m] * P[n][m]; wave 7 adds ones-row => l ----
#pragma unroll
    for (int nt = 0; nt < 4; ++nt) {
      f16x8 pf = *(const f16x8*)&P_t[(nt * 16 + lm) * 40 + g * 8];
#pragma unroll
      for (int ct = 0; ct < 4; ++ct) O[ct][nt] = MFMA16(vf[ct], pf, O[ct][nt]);
      if (wave == 7) Ol[nt] = MFMA16(ones, pf, Ol[nt]);
    }
#pragma unroll
    for (int ct = 0; ct < 4; ++ct) vf[ct] = vfn[ct];
  }

  // ---- epilogue: l from wave 7, then out = gamma*O/l + V ----
  if (wave == 7 && g == 0) {
#pragma unroll
    for (int nt = 0; nt < 4; ++nt) l_fin[nt * 16 + lm] = Ol[nt][0];
  }
  __syncthreads();
  const float gamma = gptr[0];
  const float* Vb = Vin + (size_t)b * C_ * N_;
  float* outb = out + (size_t)b * C_ * N_;
#pragma unroll
  for (int nt = 0; nt < 4; ++nt) {
    int n_g = n0 + nt * 16 + lm;
    float rl = gamma / l_fin[nt * 16 + lm];
#pragma unroll
    for (int ct = 0; ct < 4; ++ct) {
      int cbase = c0w + ct * 16 + g * 4;
#pragma unroll
      for (int r = 0; r < 4; ++r) {
        size_t idx = (size_t)(cbase + r) * N_ + n_g;
        outb[idx] = O[ct][nt][r] * rl + Vb[idx];
      }
    }
  }
}

// ---------------------------------------------------------------------------
extern "C" void kernel_launch(void* const* d_in, const int* in_sizes, int n_in,
                              void* d_out, int out_size, void* d_ws, size_t ws_size,
                              hipStream_t stream) {
  const float* Q  = (const float*)d_in[0];
  const float* K  = (const float*)d_in[1];
  const float* V  = (const float*)d_in[2];
  const float* Wq = (const float*)d_in[3];
  const float* bq = (const float*)d_in[4];
  const float* Wk = (const float*)d_in[5];
  const float* bk = (const float*)d_in[6];
  const float* Wv = (const float*)d_in[7];
  const float* bv = (const float*)d_in[8];
  const float* gm = (const float*)d_in[9];
  float* out = (float*)d_out;

  // workspace carve (~49 MB)
  char* p = (char*)d_ws;
  _Float16* wq = (_Float16*)p; p += (size_t)CH_ * C_ * 2;
  _Float16* wk = (_Float16*)p; p += (size_t)CH_ * C_ * 2;
  _Float16* wv = (_Float16*)p; p += (size_t)C_ * C_ * 2;
  _Float16* qT = (_Float16*)p; p += (size_t)B_ * N_ * CH_ * 2;
  _Float16* kT = (_Float16*)p; p += (size_t)B_ * N_ * CH_ * 2;
  _Float16* vT = (_Float16*)p; p += (size_t)B_ * C_ * N_ * 2;
  _Float16* T0 = (_Float16*)p; p += (size_t)B_ * N_ * C_ * 2;  // transpose scratch

  prep_w_kernel<<<(C_ * C_) / 256, 256, 0, stream>>>(Wq, Wk, Wv, wq, wk, wv);

  transpose_kernel<<<dim3(N_ / 64, C_ / 64, B_), 256, 0, stream>>>(Q, T0);
  proj_kernel<<<dim3(N_ / 64, 1, B_), 512, 0, stream>>>(wq, T0, bq, LOG2E, qT, CH_, 0);
  transpose_kernel<<<dim3(N_ / 64, C_ / 64, B_), 256, 0, stream>>>(K, T0);
  proj_kernel<<<dim3(N_ / 64, 1, B_), 512, 0, stream>>>(wk, T0, bk, 1.0f, kT, CH_, 0);
  transpose_kernel<<<dim3(N_ / 64, C_ / 64, B_), 256, 0, stream>>>(V, T0);
  proj_kernel<<<dim3(N_ / 64, 2, B_), 512, 0, stream>>>(wv, T0, bv, 1.0f, vT, C_, 1);

  attn_kernel<<<B_ * (N_ / 64), 512, 0, stream>>>(qT, kT, vT, V, gm, out);
}